// Round 7
// baseline (179975.720 us; speedup 1.0000x reference)
//
#include <hip/hip_runtime.h>

#define NB   64
#define NS   512
#define NE   512
#define NH   1024
#define NV   32000

__device__ __forceinline__ float sigf(float x) {
    return 1.0f / (1.0f + expf(-x));
}
__device__ __forceinline__ int clamptok(int t) {
    return t < 0 ? 0 : (t >= NV ? NV - 1 : t);
}

// ---------------------------------------------------------------------------
// init_state: copy h0 -> out h-slot (f32), c0 -> out c-slot (f32).
// grid 64 x 256, thread i covers 4 floats of each.
// ---------------------------------------------------------------------------
__global__ void init_state(const float* __restrict__ h0,
                           const float* __restrict__ c0,
                           float* __restrict__ out) {
    int i = blockIdx.x * 256 + threadIdx.x;      // 0..16383, float4 index
    float* out_h = out + 64;
    float* out_c = out + 64 + NB * NH;
    ((float4*)out_h)[i] = ((const float4*)h0)[i];
    ((float4*)out_c)[i] = ((const float4*)c0)[i];
}

// ---------------------------------------------------------------------------
// One LSTM step, pure f32 VALU. grid = 256 WGs (b in [0,64) x ug in [0,4)),
// 256 threads; thread owns unit u = ug*256 + tid for batch b.
// Computes all 4 gate dot-products (K = 1024 h-part + 512 emb-part) itself.
// h ping-pong: read hA, write hB. c updated in-place in out c-slot.
// ---------------------------------------------------------------------------
__global__ void __launch_bounds__(256)
lstm_step_simple(const int* __restrict__ x,
                 const float* __restrict__ emb,
                 const float* __restrict__ W_ih,
                 const float* __restrict__ W_hh,
                 const float* __restrict__ b_ih,
                 const float* __restrict__ b_hh,
                 const float* __restrict__ hA,   // read buffer
                 float* __restrict__ hB,         // write buffer
                 float* __restrict__ cbuf,       // in-place (out c-slot)
                 int s) {
    __shared__ float hsh[NH];
    __shared__ float esh[NE];

    const int tid = threadIdx.x;
    const int b   = blockIdx.x >> 2;
    const int ug  = blockIdx.x & 3;
    const int u   = ug * 256 + tid;

    // stage h_old[b][*] and emb[tok][*] into LDS
    {
        const float* hrow = hA + b * NH;
        float4 hv = ((const float4*)hrow)[tid];          // 4 floats each
        ((float4*)hsh)[tid] = hv;
        int tok = clamptok(x[b * NS + s]);
        const float* erow = emb + (size_t)tok * NE;
        float2 ev = ((const float2*)erow)[tid];          // 2 floats each
        ((float2*)esh)[tid] = ev;
    }
    __syncthreads();

    // 4 gate accumulators; gate rows g*NH + u in W_ih/W_hh/biases
    float acc0 = b_ih[0 * NH + u] + b_hh[0 * NH + u];
    float acc1 = b_ih[1 * NH + u] + b_hh[1 * NH + u];
    float acc2 = b_ih[2 * NH + u] + b_hh[2 * NH + u];
    float acc3 = b_ih[3 * NH + u] + b_hh[3 * NH + u];

    const float* w0 = W_hh + (size_t)(0 * NH + u) * NH;
    const float* w1 = W_hh + (size_t)(1 * NH + u) * NH;
    const float* w2 = W_hh + (size_t)(2 * NH + u) * NH;
    const float* w3 = W_hh + (size_t)(3 * NH + u) * NH;
#pragma unroll 4
    for (int k = 0; k < NH; k += 4) {
        float4 h4 = *(const float4*)(hsh + k);
        float4 a = *(const float4*)(w0 + k);
        float4 bq = *(const float4*)(w1 + k);
        float4 cq = *(const float4*)(w2 + k);
        float4 dq = *(const float4*)(w3 + k);
        acc0 += h4.x * a.x + h4.y * a.y + h4.z * a.z + h4.w * a.w;
        acc1 += h4.x * bq.x + h4.y * bq.y + h4.z * bq.z + h4.w * bq.w;
        acc2 += h4.x * cq.x + h4.y * cq.y + h4.z * cq.z + h4.w * cq.w;
        acc3 += h4.x * dq.x + h4.y * dq.y + h4.z * dq.z + h4.w * dq.w;
    }

    const float* v0 = W_ih + (size_t)(0 * NH + u) * NE;
    const float* v1 = W_ih + (size_t)(1 * NH + u) * NE;
    const float* v2 = W_ih + (size_t)(2 * NH + u) * NE;
    const float* v3 = W_ih + (size_t)(3 * NH + u) * NE;
#pragma unroll 4
    for (int k = 0; k < NE; k += 4) {
        float4 e4 = *(const float4*)(esh + k);
        float4 a = *(const float4*)(v0 + k);
        float4 bq = *(const float4*)(v1 + k);
        float4 cq = *(const float4*)(v2 + k);
        float4 dq = *(const float4*)(v3 + k);
        acc0 += e4.x * a.x + e4.y * a.y + e4.z * a.z + e4.w * a.w;
        acc1 += e4.x * bq.x + e4.y * bq.y + e4.z * bq.z + e4.w * bq.w;
        acc2 += e4.x * cq.x + e4.y * cq.y + e4.z * cq.z + e4.w * cq.w;
        acc3 += e4.x * dq.x + e4.y * dq.y + e4.z * dq.z + e4.w * dq.w;
    }

    // torch LSTMCell gate order: i, f, g, o
    float iS = sigf(acc0);
    float fS = sigf(acc1);
    float gT = tanhf(acc2);
    float oS = sigf(acc3);

    float c_old = cbuf[b * NH + u];
    float c_new = fS * c_old + iS * gT;
    // clamp: |c_ref| <= ~2, so this is semantically free; it bounds garbage.
    c_new = fminf(20.0f, fmaxf(-20.0f, c_new));
    float hN = oS * tanhf(c_new);

    cbuf[b * NH + u] = c_new;
    hB[b * NH + u]   = hN;
}

// ---------------------------------------------------------------------------
// final FC + sigmoid, f32. 1 WG x 256. thread t: b = t>>2, quarter q = t&3.
// ---------------------------------------------------------------------------
__global__ void final_fc_simple(const float* __restrict__ fc_w,
                                const float* __restrict__ fc_b,
                                float* __restrict__ out) {
    __shared__ float red[64][5];
    const float* out_h = out + 64;
    int t = threadIdx.x;
    int b = t >> 2, q = t & 3;
    const float* hp = out_h + b * NH + q * 256;
    const float* wp = fc_w + q * 256;
    float sacc = 0.f;
#pragma unroll 4
    for (int i = 0; i < 64; ++i) {
        float4 hv = ((const float4*)hp)[i];
        float4 wv = ((const float4*)wp)[i];
        sacc += hv.x * wv.x + hv.y * wv.y + hv.z * wv.z + hv.w * wv.w;
    }
    red[b][q] = sacc;
    __syncthreads();
    if (q == 0) {
        float tot = red[b][0] + red[b][1] + red[b][2] + red[b][3] + fc_b[0];
        out[b] = 1.0f / (1.0f + expf(-tot));
    }
}

extern "C" void kernel_launch(void* const* d_in, const int* in_sizes, int n_in,
                              void* d_out, int out_size, void* d_ws, size_t ws_size,
                              hipStream_t stream) {
    // documented order: x, h0, c0, emb, W_ih, W_hh, b_ih, b_hh, fc_w, fc_b
    const int*   x   = (const int*)d_in[0];
    const float* h0  = (const float*)d_in[1];
    const float* c0  = (const float*)d_in[2];
    const float* emb = (const float*)d_in[3];
    const float* Wih = (const float*)d_in[4];
    const float* Whh = (const float*)d_in[5];
    const float* bih = (const float*)d_in[6];
    const float* bhh = (const float*)d_in[7];
    const float* fcw = (const float*)d_in[8];
    const float* fcb = (const float*)d_in[9];

    float* out   = (float*)d_out;
    float* out_h = out + 64;                 // [64][1024] f32, final h slot
    float* out_c = out + 64 + NB * NH;       // [64][1024] f32, c state in-place
    float* wsH   = (float*)d_ws;             // 256 KB ping buffer for h

    hipLaunchKernelGGL(init_state, dim3(64), dim3(256), 0, stream, h0, c0, out);

    for (int s = 0; s < NS; ++s) {
        const float* hA = (s & 1) ? wsH : out_h;   // read
        float*       hB = (s & 1) ? out_h : wsH;   // write; s=511 (odd) -> out_h
        hipLaunchKernelGGL(lstm_step_simple, dim3(256), dim3(256), 0, stream,
                           x, emb, Wih, Whh, bih, bhh, hA, hB, out_c, s);
    }

    hipLaunchKernelGGL(final_fc_simple, dim3(1), dim3(256), 0, stream,
                       fcw, fcb, out);
}

// Round 8
// 15301.057 us; speedup vs baseline: 11.7623x; 11.7623x over previous
//
#include <hip/hip_runtime.h>

typedef unsigned short u16;
typedef unsigned int   u32;

typedef __bf16 bf16x8 __attribute__((ext_vector_type(8)));
typedef float  f32x4  __attribute__((ext_vector_type(4)));

#define NB   64
#define NS   512
#define NE   512
#define NH   1024
#define NK   1536
#define NV   32000

#define WPK_BYTES 12582912u     // bf16 [4096][1536]
#define HBUF_BYTES 262144u      // f32 [64][1024] ping buffer

__device__ __forceinline__ u16 f2bf(float f) {
    u32 u = __builtin_bit_cast(u32, f);
    u += 0x7fffu + ((u >> 16) & 1u);       // RNE
    return (u16)(u >> 16);
}
__device__ __forceinline__ bf16x8 pack8(float4 a, float4 b) {
    union { u16 u[8]; bf16x8 v; } o;
    o.u[0]=f2bf(a.x); o.u[1]=f2bf(a.y); o.u[2]=f2bf(a.z); o.u[3]=f2bf(a.w);
    o.u[4]=f2bf(b.x); o.u[5]=f2bf(b.y); o.u[6]=f2bf(b.z); o.u[7]=f2bf(b.w);
    return o.v;
}
__device__ __forceinline__ float sigf(float x) {
    return 1.0f / (1.0f + expf(-x));
}
__device__ __forceinline__ int clamptok(int t) {
    return t < 0 ? 0 : (t >= NV ? NV - 1 : t);
}

// ---------------------------------------------------------------------------
// init_state: h0 -> out_h (f32), c0 -> out_c (f32). 64 blocks x 256.
// ---------------------------------------------------------------------------
__global__ void init_state(const float* __restrict__ h0,
                           const float* __restrict__ c0,
                           float* __restrict__ out) {
    int i = blockIdx.x * 256 + threadIdx.x;      // float4 index, 0..16383
    float* out_h = out + 64;
    float* out_c = out + 64 + NB * NH;
    ((float4*)out_h)[i] = ((const float4*)h0)[i];
    ((float4*)out_c)[i] = ((const float4*)c0)[i];
}

// ---------------------------------------------------------------------------
// prep_pack: weights f32 -> bf16 wpk[j][k], j = gate-col row (4096),
// k in [0,1024) from W_hh[j][k], k in [1024,1536) from W_ih[j][k-1024].
// 4096 blocks x 256 (t<192 active, 8 elems each).
// ---------------------------------------------------------------------------
__global__ void prep_pack(const float* __restrict__ Wih,
                          const float* __restrict__ Whh,
                          u16* __restrict__ wpk) {
    int j = blockIdx.x, t = threadIdx.x;
    if (t >= 192) return;
    int k = t * 8;
    const float* src = (k < NH) ? (Whh + (size_t)j * NH + k)
                                : (Wih + (size_t)j * NE + (k - NH));
    float4 a  = *(const float4*)src;
    float4 b4 = *(const float4*)(src + 4);
    union { bf16x8 v; uint4 q; } o;
    o.v = pack8(a, b4);
    *(uint4*)(wpk + (size_t)j * NK + k) = o.q;
}

// ---------------------------------------------------------------------------
// One LSTM step via MFMA. 512 blocks x 256. blk = cg*4 + bg:
//   cg in [0,128): 8 hidden units -> 32 gate cols (j = g*1024 + cg*8 + uu)
//   bg in [0,4):   16 batches b0 = bg*16
// 4 waves K-split K=1536 into 12 k-tiles of 32 each.
// A (x-side): f32 h/emb packed to bf16 in-flight. B: wpk (or raw f32 pack).
// State: h f32 ping-pong (hA read / hB write), c f32 in-place in out_c.
// ---------------------------------------------------------------------------
__device__ __forceinline__ void step_core(
    const int* __restrict__ x, const float* __restrict__ emb,
    const float* __restrict__ Wih, const float* __restrict__ Whh,
    const float* __restrict__ bih, const float* __restrict__ bhh,
    const u16* __restrict__ wpk,
    const float* __restrict__ hA, float* __restrict__ hB,
    float* __restrict__ cbuf, int s, bool usePk)
{
    const int tid  = threadIdx.x;
    const int lane = tid & 63;
    const int w    = tid >> 6;             // wave 0..3
    const int blk  = blockIdx.x;
    const int cg   = blk >> 2;             // 0..127
    const int bg   = blk & 3;              // 0..3
    const int u0   = cg * 8;
    const int b0   = bg * 16;

    __shared__ float part[4][16][33];

    const int n16 = lane & 15;
    const int kq  = (lane >> 4) * 8;

    const int tok = clamptok(x[(b0 + n16) * NS + s]);

    // B-fragment rows (gate-col) for this lane's two 16-col tiles
    const int nl0 = n16, nl1 = 16 + n16;
    const int r0 = (nl0 >> 3) * NH + u0 + (nl0 & 7);
    const int r1 = (nl1 >> 3) * NH + u0 + (nl1 & 7);
    const u16* wr0 = wpk + (size_t)r0 * NK;
    const u16* wr1 = wpk + (size_t)r1 * NK;

    f32x4 acc0 = {0.f,0.f,0.f,0.f};        // cols 0..15
    f32x4 acc1 = {0.f,0.f,0.f,0.f};        // cols 16..31

#pragma unroll
    for (int tkt = 0; tkt < 12; ++tkt) {
        int kt = w * 12 + tkt;
        int ko = kt * 32 + kq;
        // ---- B fragments ----
        bf16x8 wf0, wf1;
        if (usePk) {
            wf0 = *(const bf16x8*)(wr0 + ko);
            wf1 = *(const bf16x8*)(wr1 + ko);
        } else {
            const float* s0; const float* s1;
            if (kt < 32) {
                s0 = Whh + (size_t)r0 * NH + ko;
                s1 = Whh + (size_t)r1 * NH + ko;
            } else {
                s0 = Wih + (size_t)r0 * NE + (ko - NH);
                s1 = Wih + (size_t)r1 * NE + (ko - NH);
            }
            wf0 = pack8(*(const float4*)s0, *(const float4*)(s0 + 4));
            wf1 = pack8(*(const float4*)s1, *(const float4*)(s1 + 4));
        }
        // ---- A fragment: A[m=lane&15][k=quad*8+j], batch row b0+n16 ----
        bf16x8 a0;
        if (kt < 32) {
            const float* hp = hA + (size_t)(b0 + n16) * NH + ko;
            a0 = pack8(*(const float4*)hp, *(const float4*)(hp + 4));
        } else {
            const float* ep = emb + (size_t)tok * NE + (ko - NH);
            a0 = pack8(*(const float4*)ep, *(const float4*)(ep + 4));
        }
        acc0 = __builtin_amdgcn_mfma_f32_16x16x32_bf16(a0, wf0, acc0, 0, 0, 0);
        acc1 = __builtin_amdgcn_mfma_f32_16x16x32_bf16(a0, wf1, acc1, 0, 0, 0);
    }

    {   // D layout: row m=(lane>>4)*4+r (batch), col n=lane&15 (gate col)
        int mrow = (lane >> 4) * 4;
#pragma unroll
        for (int r = 0; r < 4; ++r) {
            part[w][mrow + r][n16]      = acc0[r];
            part[w][mrow + r][16 + n16] = acc1[r];
        }
    }
    __syncthreads();

    // epilogue: threads 0..127, one per (batch mloc, unit uu)
    if (tid < 128) {
        const int mloc = tid >> 3;         // 0..15
        const int uu   = tid & 7;          // 0..7
        const int be   = b0 + mloc;
        const int je   = u0 + uu;

        float gv[4];
#pragma unroll
        for (int g = 0; g < 4; ++g) {
            int n = g * 8 + uu;
            gv[g] = part[0][mloc][n] + part[1][mloc][n]
                  + part[2][mloc][n] + part[3][mloc][n]
                  + bih[g * NH + je] + bhh[g * NH + je];
        }
        float iS = sigf(gv[0]);
        float fS = sigf(gv[1]);
        float gT = tanhf(gv[2]);
        float oS = sigf(gv[3]);
        float c_new = fS * cbuf[be * NH + je] + iS * gT;
        c_new = fminf(20.0f, fmaxf(-20.0f, c_new));    // semantically free guard
        float hN = oS * tanhf(c_new);

        cbuf[be * NH + je] = c_new;
        hB[be * NH + je]   = hN;           // s=511 is odd -> hB == out_h
    }
}

__global__ void __launch_bounds__(256)
lstm_step_pk(const int* __restrict__ x, const float* __restrict__ emb,
             const float* __restrict__ bih, const float* __restrict__ bhh,
             const u16* __restrict__ wpk,
             const float* __restrict__ hA, float* __restrict__ hB,
             float* __restrict__ cbuf, int s) {
    step_core(x, emb, nullptr, nullptr, bih, bhh, wpk, hA, hB, cbuf, s, true);
}

__global__ void __launch_bounds__(256)
lstm_step_raw(const int* __restrict__ x, const float* __restrict__ emb,
              const float* __restrict__ Wih, const float* __restrict__ Whh,
              const float* __restrict__ bih, const float* __restrict__ bhh,
              const float* __restrict__ hA, float* __restrict__ hB,
              float* __restrict__ cbuf, int s) {
    step_core(x, emb, Wih, Whh, bih, bhh, nullptr, hA, hB, cbuf, s, false);
}

// ---------------------------------------------------------------------------
// final FC + sigmoid, f32. 1 WG x 256.
// ---------------------------------------------------------------------------
__global__ void final_fc_simple(const float* __restrict__ fc_w,
                                const float* __restrict__ fc_b,
                                float* __restrict__ out) {
    __shared__ float red[64][5];
    const float* out_h = out + 64;
    int t = threadIdx.x;
    int b = t >> 2, q = t & 3;
    const float* hp = out_h + b * NH + q * 256;
    const float* wp = fc_w + q * 256;
    float sacc = 0.f;
#pragma unroll 4
    for (int i = 0; i < 64; ++i) {
        float4 hv = ((const float4*)hp)[i];
        float4 wv = ((const float4*)wp)[i];
        sacc += hv.x * wv.x + hv.y * wv.y + hv.z * wv.z + hv.w * wv.w;
    }
    red[b][q] = sacc;
    __syncthreads();
    if (q == 0) {
        float tot = red[b][0] + red[b][1] + red[b][2] + red[b][3] + fc_b[0];
        out[b] = 1.0f / (1.0f + expf(-tot));
    }
}

extern "C" void kernel_launch(void* const* d_in, const int* in_sizes, int n_in,
                              void* d_out, int out_size, void* d_ws, size_t ws_size,
                              hipStream_t stream) {
    // documented order: x, h0, c0, emb, W_ih, W_hh, b_ih, b_hh, fc_w, fc_b
    const int*   x   = (const int*)d_in[0];
    const float* h0  = (const float*)d_in[1];
    const float* c0  = (const float*)d_in[2];
    const float* emb = (const float*)d_in[3];
    const float* Wih = (const float*)d_in[4];
    const float* Whh = (const float*)d_in[5];
    const float* bih = (const float*)d_in[6];
    const float* bhh = (const float*)d_in[7];
    const float* fcw = (const float*)d_in[8];
    const float* fcb = (const float*)d_in[9];

    float* out   = (float*)d_out;
    float* out_h = out + 64;
    float* out_c = out + 64 + NB * NH;       // c state lives here in-place

    // ws tiering: [wpk 12.6MB][wsH 256KB] if it fits; else just [wsH 256KB]
    const bool haveWpk = ws_size >= (size_t)WPK_BYTES + HBUF_BYTES;
    u16*   wpk = haveWpk ? (u16*)d_ws : nullptr;
    float* wsH = haveWpk ? (float*)((char*)d_ws + WPK_BYTES) : (float*)d_ws;

    hipLaunchKernelGGL(init_state, dim3(64), dim3(256), 0, stream, h0, c0, out);

    if (haveWpk) {
        hipLaunchKernelGGL(prep_pack, dim3(4096), dim3(256), 0, stream,
                           Wih, Whh, wpk);
        for (int s = 0; s < NS; ++s) {
            const float* hA = (s & 1) ? wsH : out_h;   // read
            float*       hB = (s & 1) ? out_h : wsH;   // write; s=511 -> out_h
            hipLaunchKernelGGL(lstm_step_pk, dim3(512), dim3(256), 0, stream,
                               x, emb, bih, bhh, wpk, hA, hB, out_c, s);
        }
    } else {
        for (int s = 0; s < NS; ++s) {
            const float* hA = (s & 1) ? wsH : out_h;
            float*       hB = (s & 1) ? out_h : wsH;
            hipLaunchKernelGGL(lstm_step_raw, dim3(512), dim3(256), 0, stream,
                               x, emb, Wih, Whh, bih, bhh, hA, hB, out_c, s);
        }
    }

    hipLaunchKernelGGL(final_fc_simple, dim3(1), dim3(256), 0, stream,
                       fcw, fcb, out);
}

// Round 9
// 5201.150 us; speedup vs baseline: 34.6031x; 2.9419x over previous
//
#include <hip/hip_runtime.h>

typedef unsigned short u16;
typedef unsigned int   u32;

typedef __bf16 bf16x8 __attribute__((ext_vector_type(8)));
typedef float  f32x4  __attribute__((ext_vector_type(4)));

#define NB   64
#define NS   512
#define NE   512
#define NH   1024
#define NK   1536
#define NV   32000

#define WPKF_BYTES  12582912u   // bf16 frags [128 cg][48 kt][2 f][64 lane][8]
#define HFRAG_BYTES 262144u     // bf16 frags 2 par x [4 bg][32 kt][64 lane][8]
#define AEMBF_BYTES 33554432u   // bf16 frags [512 s][4 bg][16 kt][64 lane][8]
#define HF32_BYTES  262144u     // raw tier: f32 [64][1024] ping buffer

__device__ __forceinline__ u16 f2bf(float f) {
    u32 u = __builtin_bit_cast(u32, f);
    u += 0x7fffu + ((u >> 16) & 1u);       // RNE
    return (u16)(u >> 16);
}
__device__ __forceinline__ bf16x8 pack8(float4 a, float4 b) {
    union { u16 u[8]; bf16x8 v; } o;
    o.u[0]=f2bf(a.x); o.u[1]=f2bf(a.y); o.u[2]=f2bf(a.z); o.u[3]=f2bf(a.w);
    o.u[4]=f2bf(b.x); o.u[5]=f2bf(b.y); o.u[6]=f2bf(b.z); o.u[7]=f2bf(b.w);
    return o.v;
}
__device__ __forceinline__ float sigf(float x) {
    return 1.0f / (1.0f + expf(-x));
}
__device__ __forceinline__ int clamptok(int t) {
    return t < 0 ? 0 : (t >= NV ? NV - 1 : t);
}

// ---------------------------------------------------------------------------
// init_state: h0 -> out_h, c0 -> out_c (f32). 64 blocks x 256.
// ---------------------------------------------------------------------------
__global__ void init_state(const float* __restrict__ h0,
                           const float* __restrict__ c0,
                           float* __restrict__ out) {
    int i = blockIdx.x * 256 + threadIdx.x;      // float4 index 0..16383
    float* out_h = out + 64;
    float* out_c = out + 64 + NB * NH;
    ((float4*)out_h)[i] = ((const float4*)h0)[i];
    ((float4*)out_c)[i] = ((const float4*)c0)[i];
}

// ---------------------------------------------------------------------------
// init_hfrag: h0 (f32) -> parity-0 h fragments. 128 blocks (bg*32+kt) x 64.
// Fragment: lane = quad*16 + n16 holds h[bg*16+n16][kt*32+quad*8 .. +8].
// ---------------------------------------------------------------------------
__global__ void init_hfrag(const float* __restrict__ h0,
                           u16* __restrict__ hfrag0) {
    int blk = blockIdx.x, lane = threadIdx.x;
    int bg = blk >> 5, kt = blk & 31;
    int n16 = lane & 15, quad = lane >> 4;
    int b = bg * 16 + n16;
    int k = kt * 32 + quad * 8;
    const float* src = h0 + (size_t)b * NH + k;
    union { bf16x8 v; uint4 q; } o;
    o.v = pack8(*(const float4*)src, *(const float4*)(src + 4));
    *(uint4*)(hfrag0 + ((size_t)blk * 64 + lane) * 8) = o.q;
}

// ---------------------------------------------------------------------------
// prep_wfrag: weights f32 -> MFMA-B fragment order.
// grid 6144 (= cg*48 + kt) x 128 (f = t>>6, lane = t&63).
// B[k][n]: lane quad gives k-offset, n16 gives col; col j = (nl>>3)*NH+cg*8+(nl&7).
// ---------------------------------------------------------------------------
__global__ void prep_wfrag(const float* __restrict__ Wih,
                           const float* __restrict__ Whh,
                           u16* __restrict__ wpkf) {
    int blk = blockIdx.x, t = threadIdx.x;
    int cg = blk / 48, kt = blk % 48;
    int f = t >> 6, lane = t & 63;
    int n16 = lane & 15, quad = lane >> 4;
    int nl = f * 16 + n16;
    int j = (nl >> 3) * NH + cg * 8 + (nl & 7);
    int k = kt * 32 + quad * 8;
    const float* src = (k < NH) ? (Whh + (size_t)j * NH + k)
                                : (Wih + (size_t)j * NE + (k - NH));
    union { bf16x8 v; uint4 q; } o;
    o.v = pack8(*(const float4*)src, *(const float4*)(src + 4));
    *(uint4*)(wpkf + (((size_t)blk * 2 + f) * 64 + lane) * 8) = o.q;
}

// ---------------------------------------------------------------------------
// prep_aembf: emb gather -> bf16 A-fragment slabs.
// grid 2048 (= s*4 + bg) x 256; each thread does 4 (kt,lane) units.
// ---------------------------------------------------------------------------
__global__ void prep_aembf(const int* __restrict__ x,
                           const float* __restrict__ emb,
                           u16* __restrict__ aembf) {
    int blk = blockIdx.x, t = threadIdx.x;
    int s = blk >> 2, bg = blk & 3;
#pragma unroll
    for (int i = 0; i < 4; ++i) {
        int u = t + i * 256;               // 0..1023
        int kt16 = u >> 6, lane = u & 63;
        int n16 = lane & 15, quad = lane >> 4;
        int b = bg * 16 + n16;
        int tok = clamptok(x[b * NS + s]);
        const float* ep = emb + (size_t)tok * NE + kt16 * 32 + quad * 8;
        union { bf16x8 v; uint4 q; } o;
        o.v = pack8(*(const float4*)ep, *(const float4*)(ep + 4));
        *(uint4*)(aembf + (((size_t)blk * 16 + kt16) * 64 + lane) * 8) = o.q;
    }
}

// ---------------------------------------------------------------------------
// Fragment-path step. 512 blocks (cg*4+bg) x 256 (4 waves K-split).
// All K-loop loads are lane-contiguous 16B -> single coalesced transaction.
// EMBF: emb tiles from prepacked aembf; else in-flight f32 gather+pack.
// ---------------------------------------------------------------------------
template<bool EMBF>
__device__ __forceinline__ void step_frag_body(
    const int* __restrict__ x, const float* __restrict__ emb,
    const u16* __restrict__ wpkf, const u16* __restrict__ aembf,
    const u16* __restrict__ hfA, u16* __restrict__ hfB,
    const float* __restrict__ bih, const float* __restrict__ bhh,
    float* __restrict__ cstate, float* __restrict__ out_h, int s, int last)
{
    const int tid  = threadIdx.x;
    const int lane = tid & 63;
    const int w    = tid >> 6;
    const int blk  = blockIdx.x;
    const int cg   = blk >> 2;
    const int bg   = blk & 3;

    __shared__ float part[4][16][33];

    const int n16 = lane & 15;

    int tok = 0;
    if (!EMBF) tok = clamptok(x[(bg * 16 + n16) * NS + s]);

    const u16* wb = wpkf + (size_t)cg * 48 * 2 * 64 * 8;
    const u16* hb = hfA + (size_t)bg * 32 * 64 * 8;
    const u16* eb = EMBF ? (aembf + ((size_t)(s * 4 + bg) * 16) * 64 * 8) : nullptr;

    f32x4 acc0 = {0.f,0.f,0.f,0.f};
    f32x4 acc1 = {0.f,0.f,0.f,0.f};

#pragma unroll
    for (int tkt = 0; tkt < 12; ++tkt) {
        int kt = w * 12 + tkt;
        bf16x8 wf0 = *(const bf16x8*)(wb + ((size_t)(kt * 2 + 0) * 64 + lane) * 8);
        bf16x8 wf1 = *(const bf16x8*)(wb + ((size_t)(kt * 2 + 1) * 64 + lane) * 8);
        bf16x8 a0;
        if (kt < 32) {
            a0 = *(const bf16x8*)(hb + ((size_t)kt * 64 + lane) * 8);
        } else if (EMBF) {
            a0 = *(const bf16x8*)(eb + ((size_t)(kt - 32) * 64 + lane) * 8);
        } else {
            int kq = (lane >> 4) * 8;
            const float* ep = emb + (size_t)tok * NE + (kt - 32) * 32 + kq;
            a0 = pack8(*(const float4*)ep, *(const float4*)(ep + 4));
        }
        acc0 = __builtin_amdgcn_mfma_f32_16x16x32_bf16(a0, wf0, acc0, 0, 0, 0);
        acc1 = __builtin_amdgcn_mfma_f32_16x16x32_bf16(a0, wf1, acc1, 0, 0, 0);
    }

    {   // D layout: row m=(lane>>4)*4+r (batch), col n=lane&15 (gate col)
        int mrow = (lane >> 4) * 4;
#pragma unroll
        for (int r = 0; r < 4; ++r) {
            part[w][mrow + r][n16]      = acc0[r];
            part[w][mrow + r][16 + n16] = acc1[r];
        }
    }
    __syncthreads();

    if (tid < 128) {
        const int mloc = tid >> 3;         // 0..15 (batch in tile)
        const int uu   = tid & 7;          // 0..7  (unit in cg)
        const int be   = bg * 16 + mloc;
        const int je   = cg * 8 + uu;

        float gv[4];
#pragma unroll
        for (int g = 0; g < 4; ++g) {
            int n = g * 8 + uu;
            gv[g] = part[0][mloc][n] + part[1][mloc][n]
                  + part[2][mloc][n] + part[3][mloc][n]
                  + bih[g * NH + je] + bhh[g * NH + je];
        }
        float iS = sigf(gv[0]);
        float fS = sigf(gv[1]);
        float gT = tanhf(gv[2]);
        float oS = sigf(gv[3]);
        float c_new = fS * cstate[be * NH + je] + iS * gT;
        c_new = fminf(20.0f, fmaxf(-20.0f, c_new));   // semantically free guard
        float hN = oS * tanhf(c_new);

        cstate[be * NH + je] = c_new;

        // scatter h into next step's A-fragment layout
        int kth  = je >> 5;
        int r    = je & 31;
        int lane2 = (r >> 3) * 16 + mloc;  // quad*16 + n16
        hfB[((size_t)(bg * 32 + kth) * 64 + lane2) * 8 + (r & 7)] = f2bf(hN);

        if (last) out_h[be * NH + je] = hN;
    }
}

__global__ void __launch_bounds__(256)
step_frag_a(const u16* __restrict__ wpkf, const u16* __restrict__ aembf,
            const u16* __restrict__ hfA, u16* __restrict__ hfB,
            const float* __restrict__ bih, const float* __restrict__ bhh,
            float* __restrict__ cstate, float* __restrict__ out_h,
            int s, int last) {
    step_frag_body<true>(nullptr, nullptr, wpkf, aembf, hfA, hfB,
                         bih, bhh, cstate, out_h, s, last);
}

__global__ void __launch_bounds__(256)
step_frag_b(const int* __restrict__ x, const float* __restrict__ emb,
            const u16* __restrict__ wpkf,
            const u16* __restrict__ hfA, u16* __restrict__ hfB,
            const float* __restrict__ bih, const float* __restrict__ bhh,
            float* __restrict__ cstate, float* __restrict__ out_h,
            int s, int last) {
    step_frag_body<false>(x, emb, wpkf, nullptr, hfA, hfB,
                          bih, bhh, cstate, out_h, s, last);
}

// ---------------------------------------------------------------------------
// Raw fallback (R8-proven): f32 weights read + in-flight pack, f32 h ping.
// 512 blocks x 256.
// ---------------------------------------------------------------------------
__global__ void __launch_bounds__(256)
lstm_step_raw(const int* __restrict__ x, const float* __restrict__ emb,
              const float* __restrict__ Wih, const float* __restrict__ Whh,
              const float* __restrict__ bih, const float* __restrict__ bhh,
              const float* __restrict__ hA, float* __restrict__ hB,
              float* __restrict__ cbuf, int s) {
    const int tid  = threadIdx.x;
    const int lane = tid & 63;
    const int w    = tid >> 6;
    const int blk  = blockIdx.x;
    const int cg   = blk >> 2;
    const int bg   = blk & 3;
    const int u0   = cg * 8;
    const int b0   = bg * 16;

    __shared__ float part[4][16][33];

    const int n16 = lane & 15;
    const int kq  = (lane >> 4) * 8;
    const int tok = clamptok(x[(b0 + n16) * NS + s]);

    const int nl0 = n16, nl1 = 16 + n16;
    const int r0 = (nl0 >> 3) * NH + u0 + (nl0 & 7);
    const int r1 = (nl1 >> 3) * NH + u0 + (nl1 & 7);

    f32x4 acc0 = {0.f,0.f,0.f,0.f};
    f32x4 acc1 = {0.f,0.f,0.f,0.f};

#pragma unroll
    for (int tkt = 0; tkt < 12; ++tkt) {
        int kt = w * 12 + tkt;
        int ko = kt * 32 + kq;
        const float *s0, *s1;
        if (kt < 32) { s0 = Whh + (size_t)r0 * NH + ko; s1 = Whh + (size_t)r1 * NH + ko; }
        else         { s0 = Wih + (size_t)r0 * NE + (ko - NH); s1 = Wih + (size_t)r1 * NE + (ko - NH); }
        bf16x8 wf0 = pack8(*(const float4*)s0, *(const float4*)(s0 + 4));
        bf16x8 wf1 = pack8(*(const float4*)s1, *(const float4*)(s1 + 4));
        bf16x8 a0;
        if (kt < 32) {
            const float* hp = hA + (size_t)(b0 + n16) * NH + ko;
            a0 = pack8(*(const float4*)hp, *(const float4*)(hp + 4));
        } else {
            const float* ep = emb + (size_t)tok * NE + (ko - NH);
            a0 = pack8(*(const float4*)ep, *(const float4*)(ep + 4));
        }
        acc0 = __builtin_amdgcn_mfma_f32_16x16x32_bf16(a0, wf0, acc0, 0, 0, 0);
        acc1 = __builtin_amdgcn_mfma_f32_16x16x32_bf16(a0, wf1, acc1, 0, 0, 0);
    }

    {
        int mrow = (lane >> 4) * 4;
#pragma unroll
        for (int r = 0; r < 4; ++r) {
            part[w][mrow + r][n16]      = acc0[r];
            part[w][mrow + r][16 + n16] = acc1[r];
        }
    }
    __syncthreads();

    if (tid < 128) {
        const int mloc = tid >> 3, uu = tid & 7;
        const int be = b0 + mloc, je = u0 + uu;
        float gv[4];
#pragma unroll
        for (int g = 0; g < 4; ++g) {
            int n = g * 8 + uu;
            gv[g] = part[0][mloc][n] + part[1][mloc][n]
                  + part[2][mloc][n] + part[3][mloc][n]
                  + bih[g * NH + je] + bhh[g * NH + je];
        }
        float iS = sigf(gv[0]);
        float fS = sigf(gv[1]);
        float gT = tanhf(gv[2]);
        float oS = sigf(gv[3]);
        float c_new = fS * cbuf[be * NH + je] + iS * gT;
        c_new = fminf(20.0f, fmaxf(-20.0f, c_new));
        float hN = oS * tanhf(c_new);
        cbuf[be * NH + je] = c_new;
        hB[be * NH + je]   = hN;
    }
}

// ---------------------------------------------------------------------------
// final FC + sigmoid, f32. 1 WG x 256.
// ---------------------------------------------------------------------------
__global__ void final_fc_simple(const float* __restrict__ fc_w,
                                const float* __restrict__ fc_b,
                                float* __restrict__ out) {
    __shared__ float red[64][5];
    const float* out_h = out + 64;
    int t = threadIdx.x;
    int b = t >> 2, q = t & 3;
    const float* hp = out_h + b * NH + q * 256;
    const float* wp = fc_w + q * 256;
    float sacc = 0.f;
#pragma unroll 4
    for (int i = 0; i < 64; ++i) {
        float4 hv = ((const float4*)hp)[i];
        float4 wv = ((const float4*)wp)[i];
        sacc += hv.x * wv.x + hv.y * wv.y + hv.z * wv.z + hv.w * wv.w;
    }
    red[b][q] = sacc;
    __syncthreads();
    if (q == 0) {
        float tot = red[b][0] + red[b][1] + red[b][2] + red[b][3] + fc_b[0];
        out[b] = 1.0f / (1.0f + expf(-tot));
    }
}

extern "C" void kernel_launch(void* const* d_in, const int* in_sizes, int n_in,
                              void* d_out, int out_size, void* d_ws, size_t ws_size,
                              hipStream_t stream) {
    // order: x, h0, c0, emb, W_ih, W_hh, b_ih, b_hh, fc_w, fc_b
    const int*   x   = (const int*)d_in[0];
    const float* h0  = (const float*)d_in[1];
    const float* c0  = (const float*)d_in[2];
    const float* emb = (const float*)d_in[3];
    const float* Wih = (const float*)d_in[4];
    const float* Whh = (const float*)d_in[5];
    const float* bih = (const float*)d_in[6];
    const float* bhh = (const float*)d_in[7];
    const float* fcw = (const float*)d_in[8];
    const float* fcb = (const float*)d_in[9];

    float* out   = (float*)d_out;
    float* out_h = out + 64;
    float* out_c = out + 64 + NB * NH;       // c state in-place

    const bool tierA = ws_size >= (size_t)WPKF_BYTES + HFRAG_BYTES + AEMBF_BYTES;
    const bool tierB = !tierA && ws_size >= (size_t)WPKF_BYTES + HFRAG_BYTES;

    hipLaunchKernelGGL(init_state, dim3(64), dim3(256), 0, stream, h0, c0, out);

    if (tierA || tierB) {
        u16* wpkf  = (u16*)d_ws;
        u16* hfrag = (u16*)((char*)d_ws + WPKF_BYTES);          // 2 parities
        u16* aembf = (u16*)((char*)d_ws + WPKF_BYTES + HFRAG_BYTES);
        u16* hf0 = hfrag;                   // parity 0
        u16* hf1 = hfrag + HFRAG_BYTES / 4; // parity 1 (u16 elems: /2 bytes /2)

        hipLaunchKernelGGL(init_hfrag, dim3(128), dim3(64), 0, stream, h0, hf0);
        hipLaunchKernelGGL(prep_wfrag, dim3(6144), dim3(128), 0, stream,
                           Wih, Whh, wpkf);
        if (tierA)
            hipLaunchKernelGGL(prep_aembf, dim3(2048), dim3(256), 0, stream,
                               x, emb, aembf);

        for (int s = 0; s < NS; ++s) {
            const u16* hfA = (s & 1) ? hf1 : hf0;
            u16*       hfB = (s & 1) ? hf0 : hf1;
            int last = (s == NS - 1);
            if (tierA)
                hipLaunchKernelGGL(step_frag_a, dim3(512), dim3(256), 0, stream,
                                   wpkf, aembf, hfA, hfB, bih, bhh,
                                   out_c, out_h, s, last);
            else
                hipLaunchKernelGGL(step_frag_b, dim3(512), dim3(256), 0, stream,
                                   x, emb, wpkf, hfA, hfB, bih, bhh,
                                   out_c, out_h, s, last);
        }
    } else {
        float* wsH = (float*)d_ws;          // 256 KB f32 ping buffer
        for (int s = 0; s < NS; ++s) {
            const float* hA = (s & 1) ? wsH : out_h;
            float*       hB = (s & 1) ? out_h : wsH;   // s=511 odd -> out_h
            hipLaunchKernelGGL(lstm_step_raw, dim3(512), dim3(256), 0, stream,
                               x, emb, Wih, Whh, bih, bhh, hA, hB, out_c, s);
        }
    }

    hipLaunchKernelGGL(final_fc_simple, dim3(1), dim3(256), 0, stream,
                       fcw, fcb, out);
}

// Round 10
// 3657.874 us; speedup vs baseline: 49.2023x; 1.4219x over previous
//
#include <hip/hip_runtime.h>

typedef unsigned short u16;
typedef unsigned int   u32;

typedef __bf16 bf16x8 __attribute__((ext_vector_type(8)));
typedef float  f32x4  __attribute__((ext_vector_type(4)));

#define NB   64
#define NS   512
#define NE   512
#define NH   1024
#define NK   1536
#define NV   32000

#define WPKF_BYTES  12582912u   // bf16 frags [128 cg][48 kt][2 f][64 lane][8]
#define HFRAG_BYTES 262144u     // bf16 frags 2 par x [4 bg][32 kt][64 lane][8]
#define AEMBF_BYTES 33554432u   // bf16 frags [512 s][4 bg][16 kt][64 lane][8]
#define BSUM_BYTES  16384u      // f32 [4096] bias sum

__device__ __forceinline__ u16 f2bf(float f) {
    u32 u = __builtin_bit_cast(u32, f);
    u += 0x7fffu + ((u >> 16) & 1u);       // RNE
    return (u16)(u >> 16);
}
__device__ __forceinline__ bf16x8 pack8(float4 a, float4 b) {
    union { u16 u[8]; bf16x8 v; } o;
    o.u[0]=f2bf(a.x); o.u[1]=f2bf(a.y); o.u[2]=f2bf(a.z); o.u[3]=f2bf(a.w);
    o.u[4]=f2bf(b.x); o.u[5]=f2bf(b.y); o.u[6]=f2bf(b.z); o.u[7]=f2bf(b.w);
    return o.v;
}
__device__ __forceinline__ float sigf(float x) {
    return 1.0f / (1.0f + expf(-x));
}
__device__ __forceinline__ int clamptok(int t) {
    return t < 0 ? 0 : (t >= NV ? NV - 1 : t);
}

// ---------------------------------------------------------------------------
// init_state: h0 -> out_h, c0 -> out_c (f32). 64 blocks x 256.
// ---------------------------------------------------------------------------
__global__ void init_state(const float* __restrict__ h0,
                           const float* __restrict__ c0,
                           float* __restrict__ out) {
    int i = blockIdx.x * 256 + threadIdx.x;      // float4 index 0..16383
    float* out_h = out + 64;
    float* out_c = out + 64 + NB * NH;
    ((float4*)out_h)[i] = ((const float4*)h0)[i];
    ((float4*)out_c)[i] = ((const float4*)c0)[i];
}

// ---------------------------------------------------------------------------
// init_hfrag: h0 (f32) -> parity-0 h fragments. 128 blocks (bg*32+kt) x 64.
// ---------------------------------------------------------------------------
__global__ void init_hfrag(const float* __restrict__ h0,
                           u16* __restrict__ hfrag0) {
    int blk = blockIdx.x, lane = threadIdx.x;
    int bg = blk >> 5, kt = blk & 31;
    int n16 = lane & 15, quad = lane >> 4;
    int b = bg * 16 + n16;
    int k = kt * 32 + quad * 8;
    const float* src = h0 + (size_t)b * NH + k;
    union { bf16x8 v; uint4 q; } o;
    o.v = pack8(*(const float4*)src, *(const float4*)(src + 4));
    *(uint4*)(hfrag0 + ((size_t)blk * 64 + lane) * 8) = o.q;
}

// ---------------------------------------------------------------------------
// prep_wfrag: weights f32 -> MFMA-B fragment order.
// grid 6144 (= cg*48 + kt) x 128 (f = t>>6, lane = t&63).
// ---------------------------------------------------------------------------
__global__ void prep_wfrag(const float* __restrict__ Wih,
                           const float* __restrict__ Whh,
                           u16* __restrict__ wpkf) {
    int blk = blockIdx.x, t = threadIdx.x;
    int cg = blk / 48, kt = blk % 48;
    int f = t >> 6, lane = t & 63;
    int n16 = lane & 15, quad = lane >> 4;
    int nl = f * 16 + n16;
    int j = (nl >> 3) * NH + cg * 8 + (nl & 7);
    int k = kt * 32 + quad * 8;
    const float* src = (k < NH) ? (Whh + (size_t)j * NH + k)
                                : (Wih + (size_t)j * NE + (k - NH));
    union { bf16x8 v; uint4 q; } o;
    o.v = pack8(*(const float4*)src, *(const float4*)(src + 4));
    *(uint4*)(wpkf + (((size_t)blk * 2 + f) * 64 + lane) * 8) = o.q;
}

// ---------------------------------------------------------------------------
// prep_aembf: emb gather -> bf16 A-fragment slabs.
// grid 2048 (= s*4 + bg) x 256; each thread does 4 (kt,lane) units.
// ---------------------------------------------------------------------------
__global__ void prep_aembf(const int* __restrict__ x,
                           const float* __restrict__ emb,
                           u16* __restrict__ aembf) {
    int blk = blockIdx.x, t = threadIdx.x;
    int s = blk >> 2, bg = blk & 3;
#pragma unroll
    for (int i = 0; i < 4; ++i) {
        int u = t + i * 256;               // 0..1023
        int kt16 = u >> 6, lane = u & 63;
        int n16 = lane & 15, quad = lane >> 4;
        int b = bg * 16 + n16;
        int tok = clamptok(x[b * NS + s]);
        const float* ep = emb + (size_t)tok * NE + kt16 * 32 + quad * 8;
        union { bf16x8 v; uint4 q; } o;
        o.v = pack8(*(const float4*)ep, *(const float4*)(ep + 4));
        *(uint4*)(aembf + (((size_t)blk * 16 + kt16) * 64 + lane) * 8) = o.q;
    }
}

// ---------------------------------------------------------------------------
// prep_bsum: bsum[j] = bih[j] + bhh[j]. 16 blocks x 256.
// ---------------------------------------------------------------------------
__global__ void prep_bsum(const float* __restrict__ bih,
                          const float* __restrict__ bhh,
                          float* __restrict__ bsum) {
    int i = blockIdx.x * 256 + threadIdx.x;
    bsum[i] = bih[i] + bhh[i];
}

// ---------------------------------------------------------------------------
// Fragment-path step. 512 blocks x 256 (4 waves K-split).
// XCD swizzle: cg = blk & 127, bg = blk >> 7, so the 4 blocks sharing one
// cg's weight slice satisfy blk % 8 == cg % 8 -> same XCD -> wpkf slice
// (16 cg x 98 KB = 1.57 MB per XCD) stays L2-resident across all steps.
// ---------------------------------------------------------------------------
template<bool EMBF>
__device__ __forceinline__ void step_frag_body(
    const int* __restrict__ x, const float* __restrict__ emb,
    const u16* __restrict__ wpkf, const u16* __restrict__ aembf,
    const u16* __restrict__ hfA, u16* __restrict__ hfB,
    const float* __restrict__ bsum,
    float* __restrict__ cstate, float* __restrict__ out_h, int s, int last)
{
    const int tid  = threadIdx.x;
    const int lane = tid & 63;
    const int w    = tid >> 6;
    const int blk  = blockIdx.x;
    const int cg   = blk & 127;            // XCD swizzle (see header comment)
    const int bg   = blk >> 7;

    __shared__ float part[4][16][33];

    const int n16 = lane & 15;

    int tok = 0;
    if (!EMBF) tok = clamptok(x[(bg * 16 + n16) * NS + s]);

    const u16* wb = wpkf + (size_t)cg * 48 * 2 * 64 * 8;
    const u16* hb = hfA + (size_t)bg * 32 * 64 * 8;
    const u16* eb = EMBF ? (aembf + ((size_t)(s * 4 + bg) * 16) * 64 * 8) : nullptr;

    f32x4 acc0 = {0.f,0.f,0.f,0.f};
    f32x4 acc1 = {0.f,0.f,0.f,0.f};

#pragma unroll
    for (int tkt = 0; tkt < 12; ++tkt) {
        int kt = w * 12 + tkt;
        bf16x8 wf0 = *(const bf16x8*)(wb + ((size_t)(kt * 2 + 0) * 64 + lane) * 8);
        bf16x8 wf1 = *(const bf16x8*)(wb + ((size_t)(kt * 2 + 1) * 64 + lane) * 8);
        bf16x8 a0;
        if (kt < 32) {
            a0 = *(const bf16x8*)(hb + ((size_t)kt * 64 + lane) * 8);
        } else if (EMBF) {
            a0 = *(const bf16x8*)(eb + ((size_t)(kt - 32) * 64 + lane) * 8);
        } else {
            int kq = (lane >> 4) * 8;
            const float* ep = emb + (size_t)tok * NE + (kt - 32) * 32 + kq;
            a0 = pack8(*(const float4*)ep, *(const float4*)(ep + 4));
        }
        acc0 = __builtin_amdgcn_mfma_f32_16x16x32_bf16(a0, wf0, acc0, 0, 0, 0);
        acc1 = __builtin_amdgcn_mfma_f32_16x16x32_bf16(a0, wf1, acc1, 0, 0, 0);
    }

    {   // D layout: row m=(lane>>4)*4+r (batch), col n=lane&15 (gate col)
        int mrow = (lane >> 4) * 4;
#pragma unroll
        for (int r = 0; r < 4; ++r) {
            part[w][mrow + r][n16]      = acc0[r];
            part[w][mrow + r][16 + n16] = acc1[r];
        }
    }
    __syncthreads();

    if (tid < 128) {
        const int mloc = tid >> 3;         // 0..15 (batch in tile)
        const int uu   = tid & 7;          // 0..7  (unit in cg)
        const int be   = bg * 16 + mloc;
        const int je   = cg * 8 + uu;

        float gv[4];
#pragma unroll
        for (int g = 0; g < 4; ++g) {
            int n = g * 8 + uu;
            gv[g] = part[0][mloc][n] + part[1][mloc][n]
                  + part[2][mloc][n] + part[3][mloc][n] + bsum[g * NH + je];
        }
        float iS = sigf(gv[0]);
        float fS = sigf(gv[1]);
        float gT = tanhf(gv[2]);
        float oS = sigf(gv[3]);
        float c_new = fS * cstate[be * NH + je] + iS * gT;
        c_new = fminf(20.0f, fmaxf(-20.0f, c_new));   // semantically free guard
        float hN = oS * tanhf(c_new);

        cstate[be * NH + je] = c_new;

        // scatter h into next step's A-fragment layout
        int kth  = je >> 5;
        int r    = je & 31;
        int lane2 = (r >> 3) * 16 + mloc;  // quad*16 + n16
        hfB[((size_t)(bg * 32 + kth) * 64 + lane2) * 8 + (r & 7)] = f2bf(hN);

        if (last) out_h[be * NH + je] = hN;
    }
}

__global__ void __launch_bounds__(256)
step_frag_a(const u16* __restrict__ wpkf, const u16* __restrict__ aembf,
            const u16* __restrict__ hfA, u16* __restrict__ hfB,
            const float* __restrict__ bsum,
            float* __restrict__ cstate, float* __restrict__ out_h,
            int s, int last) {
    step_frag_body<true>(nullptr, nullptr, wpkf, aembf, hfA, hfB,
                         bsum, cstate, out_h, s, last);
}

__global__ void __launch_bounds__(256)
step_frag_b(const int* __restrict__ x, const float* __restrict__ emb,
            const u16* __restrict__ wpkf,
            const u16* __restrict__ hfA, u16* __restrict__ hfB,
            const float* __restrict__ bsum,
            float* __restrict__ cstate, float* __restrict__ out_h,
            int s, int last) {
    step_frag_body<false>(x, emb, wpkf, nullptr, hfA, hfB,
                          bsum, cstate, out_h, s, last);
}

// ---------------------------------------------------------------------------
// Raw fallback (R8-proven): f32 weights read + in-flight pack, f32 h ping.
// ---------------------------------------------------------------------------
__global__ void __launch_bounds__(256)
lstm_step_raw(const int* __restrict__ x, const float* __restrict__ emb,
              const float* __restrict__ Wih, const float* __restrict__ Whh,
              const float* __restrict__ bih, const float* __restrict__ bhh,
              const float* __restrict__ hA, float* __restrict__ hB,
              float* __restrict__ cbuf, int s) {
    const int tid  = threadIdx.x;
    const int lane = tid & 63;
    const int w    = tid >> 6;
    const int blk  = blockIdx.x;
    const int cg   = blk & 127;
    const int bg   = blk >> 7;
    const int u0   = cg * 8;
    const int b0   = bg * 16;

    __shared__ float part[4][16][33];

    const int n16 = lane & 15;
    const int kq  = (lane >> 4) * 8;
    const int tok = clamptok(x[(b0 + n16) * NS + s]);

    const int nl0 = n16, nl1 = 16 + n16;
    const int r0 = (nl0 >> 3) * NH + u0 + (nl0 & 7);
    const int r1 = (nl1 >> 3) * NH + u0 + (nl1 & 7);

    f32x4 acc0 = {0.f,0.f,0.f,0.f};
    f32x4 acc1 = {0.f,0.f,0.f,0.f};

#pragma unroll
    for (int tkt = 0; tkt < 12; ++tkt) {
        int kt = w * 12 + tkt;
        int ko = kt * 32 + kq;
        const float *s0, *s1;
        if (kt < 32) { s0 = Whh + (size_t)r0 * NH + ko; s1 = Whh + (size_t)r1 * NH + ko; }
        else         { s0 = Wih + (size_t)r0 * NE + (ko - NH); s1 = Wih + (size_t)r1 * NE + (ko - NH); }
        bf16x8 wf0 = pack8(*(const float4*)s0, *(const float4*)(s0 + 4));
        bf16x8 wf1 = pack8(*(const float4*)s1, *(const float4*)(s1 + 4));
        bf16x8 a0;
        if (kt < 32) {
            const float* hp = hA + (size_t)(b0 + n16) * NH + ko;
            a0 = pack8(*(const float4*)hp, *(const float4*)(hp + 4));
        } else {
            const float* ep = emb + (size_t)tok * NE + (ko - NH);
            a0 = pack8(*(const float4*)ep, *(const float4*)(ep + 4));
        }
        acc0 = __builtin_amdgcn_mfma_f32_16x16x32_bf16(a0, wf0, acc0, 0, 0, 0);
        acc1 = __builtin_amdgcn_mfma_f32_16x16x32_bf16(a0, wf1, acc1, 0, 0, 0);
    }

    {
        int mrow = (lane >> 4) * 4;
#pragma unroll
        for (int r = 0; r < 4; ++r) {
            part[w][mrow + r][n16]      = acc0[r];
            part[w][mrow + r][16 + n16] = acc1[r];
        }
    }
    __syncthreads();

    if (tid < 128) {
        const int mloc = tid >> 3, uu = tid & 7;
        const int be = b0 + mloc, je = u0 + uu;
        float gv[4];
#pragma unroll
        for (int g = 0; g < 4; ++g) {
            int n = g * 8 + uu;
            gv[g] = part[0][mloc][n] + part[1][mloc][n]
                  + part[2][mloc][n] + part[3][mloc][n]
                  + bih[g * NH + je] + bhh[g * NH + je];
        }
        float iS = sigf(gv[0]);
        float fS = sigf(gv[1]);
        float gT = tanhf(gv[2]);
        float oS = sigf(gv[3]);
        float c_new = fS * cbuf[be * NH + je] + iS * gT;
        c_new = fminf(20.0f, fmaxf(-20.0f, c_new));
        float hN = oS * tanhf(c_new);
        cbuf[be * NH + je] = c_new;
        hB[be * NH + je]   = hN;
    }
}

// ---------------------------------------------------------------------------
// final FC + sigmoid, f32. 1 WG x 256.
// ---------------------------------------------------------------------------
__global__ void final_fc_simple(const float* __restrict__ fc_w,
                                const float* __restrict__ fc_b,
                                float* __restrict__ out) {
    __shared__ float red[64][5];
    const float* out_h = out + 64;
    int t = threadIdx.x;
    int b = t >> 2, q = t & 3;
    const float* hp = out_h + b * NH + q * 256;
    const float* wp = fc_w + q * 256;
    float sacc = 0.f;
#pragma unroll 4
    for (int i = 0; i < 64; ++i) {
        float4 hv = ((const float4*)hp)[i];
        float4 wv = ((const float4*)wp)[i];
        sacc += hv.x * wv.x + hv.y * wv.y + hv.z * wv.z + hv.w * wv.w;
    }
    red[b][q] = sacc;
    __syncthreads();
    if (q == 0) {
        float tot = red[b][0] + red[b][1] + red[b][2] + red[b][3] + fc_b[0];
        out[b] = 1.0f / (1.0f + expf(-tot));
    }
}

extern "C" void kernel_launch(void* const* d_in, const int* in_sizes, int n_in,
                              void* d_out, int out_size, void* d_ws, size_t ws_size,
                              hipStream_t stream) {
    // order: x, h0, c0, emb, W_ih, W_hh, b_ih, b_hh, fc_w, fc_b
    const int*   x   = (const int*)d_in[0];
    const float* h0  = (const float*)d_in[1];
    const float* c0  = (const float*)d_in[2];
    const float* emb = (const float*)d_in[3];
    const float* Wih = (const float*)d_in[4];
    const float* Whh = (const float*)d_in[5];
    const float* bih = (const float*)d_in[6];
    const float* bhh = (const float*)d_in[7];
    const float* fcw = (const float*)d_in[8];
    const float* fcb = (const float*)d_in[9];

    float* out   = (float*)d_out;
    float* out_h = out + 64;
    float* out_c = out + 64 + NB * NH;       // c state in-place

    const size_t needA = (size_t)WPKF_BYTES + HFRAG_BYTES + AEMBF_BYTES + BSUM_BYTES;
    const size_t needB = (size_t)WPKF_BYTES + HFRAG_BYTES + BSUM_BYTES;
    const bool tierA = ws_size >= needA;
    const bool tierB = !tierA && ws_size >= needB;

    hipLaunchKernelGGL(init_state, dim3(64), dim3(256), 0, stream, h0, c0, out);

    if (tierA || tierB) {
        u16* wpkf  = (u16*)d_ws;
        u16* hfrag = (u16*)((char*)d_ws + WPKF_BYTES);
        u16* hf0 = hfrag;
        u16* hf1 = hfrag + HFRAG_BYTES / 4;  // u16 elems: bytes/2 per parity
        char* after = (char*)d_ws + WPKF_BYTES + HFRAG_BYTES;
        u16*   aembf = tierA ? (u16*)after : nullptr;
        float* bsum  = (float*)(after + (tierA ? AEMBF_BYTES : 0));

        hipLaunchKernelGGL(init_hfrag, dim3(128), dim3(64), 0, stream, h0, hf0);
        hipLaunchKernelGGL(prep_wfrag, dim3(6144), dim3(128), 0, stream,
                           Wih, Whh, wpkf);
        hipLaunchKernelGGL(prep_bsum, dim3(16), dim3(256), 0, stream,
                           bih, bhh, bsum);
        if (tierA)
            hipLaunchKernelGGL(prep_aembf, dim3(2048), dim3(256), 0, stream,
                               x, emb, aembf);

        for (int s = 0; s < NS; ++s) {
            const u16* hfA = (s & 1) ? hf1 : hf0;
            u16*       hfB = (s & 1) ? hf0 : hf1;
            int last = (s == NS - 1);
            if (tierA)
                hipLaunchKernelGGL(step_frag_a, dim3(512), dim3(256), 0, stream,
                                   wpkf, aembf, hfA, hfB, bsum,
                                   out_c, out_h, s, last);
            else
                hipLaunchKernelGGL(step_frag_b, dim3(512), dim3(256), 0, stream,
                                   x, emb, wpkf, hfA, hfB, bsum,
                                   out_c, out_h, s, last);
        }
    } else {
        float* wsH = (float*)d_ws;          // 256 KB f32 ping buffer
        for (int s = 0; s < NS; ++s) {
            const float* hA = (s & 1) ? wsH : out_h;
            float*       hB = (s & 1) ? out_h : wsH;   // s=511 odd -> out_h
            hipLaunchKernelGGL(lstm_step_raw, dim3(512), dim3(256), 0, stream,
                               x, emb, Wih, Whh, bih, bhh, hA, hB, out_c, s);
        }
    }

    hipLaunchKernelGGL(final_fc_simple, dim3(1), dim3(256), 0, stream,
                       fcw, fcb, out);
}